// Round 6
// baseline (83.982 us; speedup 1.0000x reference)
//
#include <hip/hip_runtime.h>
#include <math.h>

// Every rounding is deliberate: bit-match the reference fp32 pipeline
// (ascending single-accumulator FMA dot — verified rounds 4/5, absmax=0).
#pragma clang fp contract(off)

constexpr int KCODES = 2048;   // EMBEDDING_LENGTH
constexpr int CDIM   = 4;      // EMBEDDING_DIM
constexpr int KSPLIT = 8;      // one k-chunk per wave
constexpr int KCHUNK = KCODES / KSPLIT;  // 256 codes per wave
constexpr int ROWS   = 64;     // rows per block (= lanes per wave)

// ---------- prep: [float4 e] and [e2sum] tables in separate restrict arrays --
__global__ __launch_bounds__(256) void vq_prep(
    const float* __restrict__ emb, float4* __restrict__ tE, float* __restrict__ tS)
{
    int i = blockIdx.x * 256 + threadIdx.x;
    if (i < KCODES) {
        float4 e = reinterpret_cast<const float4*>(emb)[i];
        tE[i] = e;
        tS[i] = ((e.x * e.x + e.y * e.y) + e.z * e.z) + e.w * e.w;
    }
}

// ---------- main: 8 waves/block, wave w owns k-chunk w for the block's 64 rows.
// Embedding index is wave-uniform -> backend scalarizes to s_load (SGPR
// operands, ~9 VALU/code). In-block u64-key min-reduce across waves in LDS.
__global__ __launch_bounds__(512) void vq_main(
    const float* __restrict__ x,
    const float4* __restrict__ tE,
    const float* __restrict__ tS,
    int* __restrict__ out,
    int N)
{
    __shared__ unsigned long long skey[ROWS][KSPLIT];   // 4 KB

    const int t    = threadIdx.x;
    const int wid  = t >> 6;        // wave id == k-chunk id (wave-uniform)
    const int lane = t & 63;        // row within block
    const int n    = blockIdx.x * ROWS + lane;
    const int kbase = wid * KCHUNK;

    unsigned long long key = ~0ull;
    if (n < N) {
        const float4 xv = reinterpret_cast<const float4*>(x)[n];
        const float x2 = ((xv.x * xv.x + xv.y * xv.y) + xv.z * xv.z) + xv.w * xv.w;

        const float4* __restrict__ eptr = tE + kbase;
        const float*  __restrict__ sptr = tS + kbase;

        // 4 independent (min, idx) chains for ILP.
        float dmin[4] = {HUGE_VALF, HUGE_VALF, HUGE_VALF, HUGE_VALF};
        int   bi[4]   = {0, 0, 0, 0};

        #pragma unroll 4
        for (int i = 0; i < KCHUNK / 4; ++i) {
            #pragma unroll
            for (int u = 0; u < 4; ++u) {
                const float4 e = eptr[i * 4 + u];   // wave-uniform -> s_load
                // ascending FMA chain (reference pipeline)
                float dot = xv.x * e.x;
                dot = __builtin_fmaf(xv.y, e.y, dot);
                dot = __builtin_fmaf(xv.z, e.z, dot);
                dot = __builtin_fmaf(xv.w, e.w, dot);
                float tmp = __builtin_fmaf(-2.0f, dot, x2);  // == x2 - 2*dot
                float d = tmp + sptr[i * 4 + u];
                if (d < dmin[u]) { dmin[u] = d; bi[u] = i; } // strict <: first occ.
            }
        }

        // Merge chains; smaller global index wins exact ties (np.argmin).
        float bm = dmin[0];
        int   bidx = kbase + (bi[0] << 2) + 0;
        #pragma unroll
        for (int u = 1; u < 4; ++u) {
            int idx_u = kbase + (bi[u] << 2) + u;
            if (dmin[u] < bm || (dmin[u] == bm && idx_u < bidx)) {
                bm = dmin[u]; bidx = idx_u;
            }
        }

        // d >= 0 here, so float bits are order-isomorphic as u32; low bits
        // break exact ties toward the smaller index.
        key = ((unsigned long long)__float_as_uint(bm) << 32) | (unsigned)bidx;
    }
    skey[lane][wid] = key;
    __syncthreads();

    // First 64 threads: u64-min across the 8 wave partials, emit index.
    if (t < ROWS) {
        const int rn = blockIdx.x * ROWS + t;
        if (rn < N) {
            unsigned long long k = skey[t][0];
            #pragma unroll
            for (int s = 1; s < KSPLIT; ++s) {
                unsigned long long v = skey[t][s];
                if (v < k) k = v;
            }
            out[rn] = (int)(unsigned)(k & 0xFFFFFFFFull);
        }
    }
}

// ---------- fallback single kernel (round-4, known-good) ----------
__global__ __launch_bounds__(256) void vq_argmin_fallback(
    const float* __restrict__ x, const float* __restrict__ emb,
    int* __restrict__ out, int N)
{
    __shared__ float4 sE[KCODES];
    __shared__ float  sE2[KCODES];
    const int t = threadIdx.x;
    for (int i = t; i < KCODES; i += 256) {
        float4 e = reinterpret_cast<const float4*>(emb)[i];
        sE[i] = e;
        sE2[i] = ((e.x * e.x + e.y * e.y) + e.z * e.z) + e.w * e.w;
    }
    __syncthreads();
    const int n = blockIdx.x * 256 + t;
    if (n >= N) return;
    const float4 xv = reinterpret_cast<const float4*>(x)[n];
    const float x2 = ((xv.x * xv.x + xv.y * xv.y) + xv.z * xv.z) + xv.w * xv.w;
    float dmin[4] = {HUGE_VALF, HUGE_VALF, HUGE_VALF, HUGE_VALF};
    int bidx[4] = {0, 0, 0, 0};
    for (int k = 0; k < KCODES; k += 4) {
        #pragma unroll
        for (int u = 0; u < 4; ++u) {
            const float4 e = sE[k + u];
            float dot = xv.x * e.x;
            dot = __builtin_fmaf(xv.y, e.y, dot);
            dot = __builtin_fmaf(xv.z, e.z, dot);
            dot = __builtin_fmaf(xv.w, e.w, dot);
            float tmp = __builtin_fmaf(-2.0f, dot, x2);
            float d = tmp + sE2[k + u];
            if (d < dmin[u]) { dmin[u] = d; bidx[u] = k + u; }
        }
    }
    float bm = dmin[0]; int bi = bidx[0];
    #pragma unroll
    for (int u = 1; u < 4; ++u)
        if (dmin[u] < bm || (dmin[u] == bm && bidx[u] < bi)) { bm = dmin[u]; bi = bidx[u]; }
    out[n] = bi;
}

extern "C" void kernel_launch(void* const* d_in, const int* in_sizes, int n_in,
                              void* d_out, int out_size, void* d_ws, size_t ws_size,
                              hipStream_t stream) {
    const float* x   = (const float*)d_in[0];   // [16,64,64,4] -> [N,4]
    const float* emb = (const float*)d_in[1];   // [2048,4]
    int* out = (int*)d_out;                     // [N] int32
    const int N = in_sizes[0] / CDIM;           // 65536

    // ws layout: [0,32K) tE  [32K,40K) tS
    const size_t need = 40960;
    if (ws_size < need) {
        vq_argmin_fallback<<<(N + 255) / 256, 256, 0, stream>>>(x, emb, out, N);
        return;
    }
    char* ws = (char*)d_ws;
    float4* tE = (float4*)(ws);
    float*  tS = (float*)(ws + 32768);

    vq_prep<<<(KCODES + 255) / 256, 256, 0, stream>>>(emb, tE, tS);
    vq_main<<<(N + ROWS - 1) / ROWS, 512, 0, stream>>>(x, tE, tS, out, N);
}

// Round 7
// 38.642 us; speedup vs baseline: 2.1733x; 2.1733x over previous
//
#include <hip/hip_runtime.h>
#include <math.h>

// Every rounding is deliberate: bit-match the reference fp32 pipeline
// (ascending single-accumulator FMA dot — verified rounds 4-6, absmax=0).
#pragma clang fp contract(off)

constexpr int KCODES = 2048;   // EMBEDDING_LENGTH
constexpr int CDIM   = 4;      // EMBEDDING_DIM
constexpr int KSPLIT = 8;      // one k-chunk per wave
constexpr int KCHUNK = KCODES / KSPLIT;  // 256 codes per wave
constexpr int ROWS   = 64;     // rows per block (= lanes per wave)

// ---------- prep: [float4 e] and [e2sum] tables in separate restrict arrays --
__global__ __launch_bounds__(256) void vq_prep(
    const float* __restrict__ emb, float4* __restrict__ tE, float* __restrict__ tS)
{
    int i = blockIdx.x * 256 + threadIdx.x;
    if (i < KCODES) {
        float4 e = reinterpret_cast<const float4*>(emb)[i];
        tE[i] = e;
        tS[i] = ((e.x * e.x + e.y * e.y) + e.z * e.z) + e.w * e.w;
    }
}

// ---------- main: 8 waves/block, wave w owns k-chunk w for the block's 64 rows.
// kbase forced uniform via readfirstlane so the embedding reads scalarize to
// s_load (SGPR operands) — round 6 lost this (SGPR 96->32) because
// threadIdx.x>>6 is not provably wave-uniform to the divergence analysis.
__global__ __launch_bounds__(512) void vq_main(
    const float* __restrict__ x,
    const float4* __restrict__ tE,
    const float* __restrict__ tS,
    int* __restrict__ out,
    int N)
{
    __shared__ unsigned long long skey[ROWS][KSPLIT + 1];   // +1: break bank conflict

    const int t    = threadIdx.x;
    const int lane = t & 63;        // row within block
    const int n    = blockIdx.x * ROWS + lane;
    // wave id == k-chunk id; provably uniform via readfirstlane -> SGPR
    const int wid   = __builtin_amdgcn_readfirstlane(t >> 6);
    const int kbase = wid * KCHUNK;

    unsigned long long key = ~0ull;
    if (n < N) {
        const float4 xv = reinterpret_cast<const float4*>(x)[n];
        const float x2 = ((xv.x * xv.x + xv.y * xv.y) + xv.z * xv.z) + xv.w * xv.w;

        const float4* __restrict__ eptr = tE + kbase;
        const float*  __restrict__ sptr = tS + kbase;

        // 4 independent (min, idx) chains for ILP.
        float dmin[4] = {HUGE_VALF, HUGE_VALF, HUGE_VALF, HUGE_VALF};
        int   bi[4]   = {0, 0, 0, 0};

        #pragma unroll 4
        for (int i = 0; i < KCHUNK / 4; ++i) {
            #pragma unroll
            for (int u = 0; u < 4; ++u) {
                const float4 e = eptr[i * 4 + u];   // uniform addr -> s_load
                // ascending FMA chain (reference pipeline)
                float dot = xv.x * e.x;
                dot = __builtin_fmaf(xv.y, e.y, dot);
                dot = __builtin_fmaf(xv.z, e.z, dot);
                dot = __builtin_fmaf(xv.w, e.w, dot);
                float tmp = __builtin_fmaf(-2.0f, dot, x2);  // == x2 - 2*dot
                float d = tmp + sptr[i * 4 + u];
                if (d < dmin[u]) { dmin[u] = d; bi[u] = i; } // strict <: first occ.
            }
        }

        // Merge chains; smaller global index wins exact ties (np.argmin).
        float bm = dmin[0];
        int   bidx = kbase + (bi[0] << 2) + 0;
        #pragma unroll
        for (int u = 1; u < 4; ++u) {
            int idx_u = kbase + (bi[u] << 2) + u;
            if (dmin[u] < bm || (dmin[u] == bm && idx_u < bidx)) {
                bm = dmin[u]; bidx = idx_u;
            }
        }

        // d >= 0 here, so float bits are order-isomorphic as u32; low bits
        // break exact ties toward the smaller index.
        key = ((unsigned long long)__float_as_uint(bm) << 32) | (unsigned)bidx;
    }
    skey[lane][wid] = key;
    __syncthreads();

    // First 64 threads: u64-min across the 8 wave partials, emit index.
    if (t < ROWS) {
        const int rn = blockIdx.x * ROWS + t;
        if (rn < N) {
            unsigned long long k = skey[t][0];
            #pragma unroll
            for (int s = 1; s < KSPLIT; ++s) {
                unsigned long long v = skey[t][s];
                if (v < k) k = v;
            }
            out[rn] = (int)(unsigned)(k & 0xFFFFFFFFull);
        }
    }
}

// ---------- fallback single kernel (round-4, known-good) ----------
__global__ __launch_bounds__(256) void vq_argmin_fallback(
    const float* __restrict__ x, const float* __restrict__ emb,
    int* __restrict__ out, int N)
{
    __shared__ float4 sE[KCODES];
    __shared__ float  sE2[KCODES];
    const int t = threadIdx.x;
    for (int i = t; i < KCODES; i += 256) {
        float4 e = reinterpret_cast<const float4*>(emb)[i];
        sE[i] = e;
        sE2[i] = ((e.x * e.x + e.y * e.y) + e.z * e.z) + e.w * e.w;
    }
    __syncthreads();
    const int n = blockIdx.x * 256 + t;
    if (n >= N) return;
    const float4 xv = reinterpret_cast<const float4*>(x)[n];
    const float x2 = ((xv.x * xv.x + xv.y * xv.y) + xv.z * xv.z) + xv.w * xv.w;
    float dmin[4] = {HUGE_VALF, HUGE_VALF, HUGE_VALF, HUGE_VALF};
    int bidx[4] = {0, 0, 0, 0};
    for (int k = 0; k < KCODES; k += 4) {
        #pragma unroll
        for (int u = 0; u < 4; ++u) {
            const float4 e = sE[k + u];
            float dot = xv.x * e.x;
            dot = __builtin_fmaf(xv.y, e.y, dot);
            dot = __builtin_fmaf(xv.z, e.z, dot);
            dot = __builtin_fmaf(xv.w, e.w, dot);
            float tmp = __builtin_fmaf(-2.0f, dot, x2);
            float d = tmp + sE2[k + u];
            if (d < dmin[u]) { dmin[u] = d; bidx[u] = k + u; }
        }
    }
    float bm = dmin[0]; int bi = bidx[0];
    #pragma unroll
    for (int u = 1; u < 4; ++u)
        if (dmin[u] < bm || (dmin[u] == bm && bidx[u] < bi)) { bm = dmin[u]; bi = bidx[u]; }
    out[n] = bi;
}

extern "C" void kernel_launch(void* const* d_in, const int* in_sizes, int n_in,
                              void* d_out, int out_size, void* d_ws, size_t ws_size,
                              hipStream_t stream) {
    const float* x   = (const float*)d_in[0];   // [16,64,64,4] -> [N,4]
    const float* emb = (const float*)d_in[1];   // [2048,4]
    int* out = (int*)d_out;                     // [N] int32
    const int N = in_sizes[0] / CDIM;           // 65536

    // ws layout: [0,32K) tE  [32K,40K) tS
    const size_t need = 40960;
    if (ws_size < need) {
        vq_argmin_fallback<<<(N + 255) / 256, 256, 0, stream>>>(x, emb, out, N);
        return;
    }
    char* ws = (char*)d_ws;
    float4* tE = (float4*)(ws);
    float*  tS = (float*)(ws + 32768);

    vq_prep<<<(KCODES + 255) / 256, 256, 0, stream>>>(emb, tE, tS);
    vq_main<<<(N + ROWS - 1) / ROWS, 512, 0, stream>>>(x, tE, tS, out, N);
}